// Round 14
// baseline (267.652 us; speedup 1.0000x reference)
//
#include <hip/hip_runtime.h>
#include <math.h>

#define TPB 256
#define NBLK 512
#define HALF_LOG_2PI 0.91893853320467274178f

// ws float layout: [0]=cnt1(u32) [1]=cnt2(u32) [2]=lpsum [8..39]=gsum[32]
// All zeroed by a hipMemsetAsync node before the kernel each call.

__global__ __launch_bounds__(TPB, 2) void fused_kernel(
    const float* __restrict__ O, int n_ctx,
    const float* __restrict__ T, int n_tgt,
    const float* __restrict__ hW0, const float* __restrict__ hb0,
    const float* __restrict__ hW1, const float* __restrict__ hb1,
    const float* __restrict__ hW2, const float* __restrict__ hb2,
    const float* __restrict__ gW0, const float* __restrict__ gb0,
    const float* __restrict__ gW1, const float* __restrict__ gb1,
    const float* __restrict__ gW2, const float* __restrict__ gb2,
    const float* __restrict__ gW3, const float* __restrict__ gb3,
    const float* __restrict__ gW4, const float* __restrict__ gb4,
    unsigned* __restrict__ cnt1, unsigned* __restrict__ cnt2,
    float* __restrict__ lpsum, float* __restrict__ gsum,
    float* __restrict__ phi, float* __restrict__ outlp)
{
    // ---- stage all weights into LDS (once) ----
    __shared__ __align__(16) float sEW0[16], sEB0[8], sEW1[256], sEB1[32];
    __shared__ __align__(16) float sW1[2048], sB1[32], sW2[512], sB2[16];
    __shared__ __align__(16) float sW3[128], sB3[8], sW4[16], sB4[2];
    __shared__ __align__(16) float2 sL0[64];
    __shared__ float a2m[32], rl[128];
    __shared__ float xred[TPB / 64][32];
    __shared__ float lred[TPB / 64];

    int tid = threadIdx.x;
    ((float4*)sW1)[tid]       = ((const float4*)gW1)[tid];         // 512 quads
    ((float4*)sW1)[256 + tid] = ((const float4*)gW1)[256 + tid];
    if (tid < 128) ((float4*)sW2)[tid] = ((const float4*)gW2)[tid];
    if (tid < 32)  ((float4*)sW3)[tid] = ((const float4*)gW3)[tid];
    if (tid < 32)  sB1[tid] = gb1[tid];
    if (tid < 16)  sB2[tid] = gb2[tid];
    if (tid < 8)   sB3[tid] = gb3[tid];
    if (tid < 16)  sW4[tid] = gW4[tid];
    if (tid < 2)   sB4[tid] = gb4[tid];
    if (tid < 16)  sEW0[tid] = hW0[tid];
    if (tid < 8)   sEB0[tid] = hb0[tid];
    if (tid < 64)  ((float4*)sEW1)[tid] = ((const float4*)hW1)[tid];
    if (tid < 32)  sEB1[tid] = hb1[tid];
    __syncthreads();

    int nthreads = gridDim.x * TPB;
    int gid = blockIdx.x * TPB + tid;
    int lane = tid & 63, wv = tid >> 6;

    // ---- phase 1: encoder (grid-stride), accumulate relu(a1) column sums ----
    float acc[32];
#pragma unroll
    for (int k = 0; k < 32; ++k) acc[k] = 0.f;
    for (int row = gid; row < n_ctx; row += nthreads) {
        float2 o = ((const float2*)O)[row];
        float a1[32];
#pragma unroll
        for (int k = 0; k < 32; ++k) a1[k] = sEB1[k];
#pragma unroll
        for (int j = 0; j < 8; ++j) {
            float a0 = fmaxf(fmaf(o.x, sEW0[j], fmaf(o.y, sEW0[8 + j], sEB0[j])), 0.f);
#pragma unroll
            for (int kq = 0; kq < 8; ++kq) {
                float4 w = ((const float4*)sEW1)[j * 8 + kq];
                a1[kq * 4 + 0] = fmaf(a0, w.x, a1[kq * 4 + 0]);
                a1[kq * 4 + 1] = fmaf(a0, w.y, a1[kq * 4 + 1]);
                a1[kq * 4 + 2] = fmaf(a0, w.z, a1[kq * 4 + 2]);
                a1[kq * 4 + 3] = fmaf(a0, w.w, a1[kq * 4 + 3]);
            }
        }
#pragma unroll
        for (int k = 0; k < 32; ++k) acc[k] += fmaxf(a1[k], 0.f);
    }
#pragma unroll
    for (int k = 0; k < 32; ++k) {
        float v = acc[k];
#pragma unroll
        for (int m = 32; m >= 1; m >>= 1) v += __shfl_xor(v, m, 64);
        acc[k] = v;
    }
    if (lane == 0) {
#pragma unroll
        for (int k = 0; k < 32; ++k) xred[wv][k] = acc[k];
    }
    __syncthreads();
    if (tid < 32) {
        float s = 0.f;
#pragma unroll
        for (int w = 0; w < TPB / 64; ++w) s += xred[w][tid];
        atomicAdd(&gsum[tid], s);
    }

    // ---- grid-wide barrier (fence + ticket spin; 512 blocks co-resident) ----
    __threadfence();
    __syncthreads();
    if (tid == 0) {
        atomicAdd(cnt1, 1u);
        while (atomicAdd(cnt1, 0u) < gridDim.x) { __builtin_amdgcn_s_sleep(2); }
    }
    __syncthreads();

    // ---- phase 2: mid (redundant per block; needs only the 32 global sums) ----
    if (tid < 32) a2m[tid] = atomicAdd(&gsum[tid], 0.0f) / (float)n_ctx;
    __syncthreads();
    if (tid < 128) {
        float v = hb2[tid];
#pragma unroll
        for (int j = 0; j < 32; ++j) v = fmaf(a2m[j], hW2[j * 128 + tid], v);
        rl[tid] = v;
    }
    __syncthreads();
    if (tid < 64) {
        float v = gb0[tid];
#pragma unroll
        for (int i = 0; i < 128; ++i) v = fmaf(rl[i], gW0[i * 64 + tid], v);
        sL0[tid] = make_float2(v, gW0[128 * 64 + tid]);   // (rW0[j], gW0[128][j])
    }
    __syncthreads();

    // ---- phase 3: decoder, 2 rows per thread per sweep (single sweep here) ----
    float lp_acc = 0.f;
    for (int base = 0; base < n_tgt; base += 2 * nthreads) {
        int r0 = base + gid, r1 = r0 + nthreads;
        bool v0 = r0 < n_tgt, v1 = r1 < n_tgt;
        float2 t0 = v0 ? ((const float2*)T)[r0] : make_float2(0.f, 0.f);
        float2 t1 = v1 ? ((const float2*)T)[r1] : make_float2(0.f, 0.f);
        float x[2] = { t0.x, t1.x }, y[2] = { t0.y, t1.y };

        float a1[2][32];
#pragma unroll
        for (int r = 0; r < 2; ++r)
#pragma unroll
            for (int k = 0; k < 32; ++k) a1[r][k] = sB1[k];
#pragma unroll 4
        for (int j = 0; j < 64; ++j) {
            float2 l0 = sL0[j];
            float a0[2];
#pragma unroll
            for (int r = 0; r < 2; ++r)
                a0[r] = fmaxf(fmaf(x[r], l0.y, l0.x), 0.f);
#pragma unroll
            for (int kq = 0; kq < 8; ++kq) {
                float4 w = ((const float4*)sW1)[j * 8 + kq];
#pragma unroll
                for (int r = 0; r < 2; ++r) {
                    a1[r][kq * 4 + 0] = fmaf(a0[r], w.x, a1[r][kq * 4 + 0]);
                    a1[r][kq * 4 + 1] = fmaf(a0[r], w.y, a1[r][kq * 4 + 1]);
                    a1[r][kq * 4 + 2] = fmaf(a0[r], w.z, a1[r][kq * 4 + 2]);
                    a1[r][kq * 4 + 3] = fmaf(a0[r], w.w, a1[r][kq * 4 + 3]);
                }
            }
        }
#pragma unroll
        for (int r = 0; r < 2; ++r)
#pragma unroll
            for (int k = 0; k < 32; ++k) a1[r][k] = fmaxf(a1[r][k], 0.f);

        float a2[2][16];
#pragma unroll
        for (int r = 0; r < 2; ++r)
#pragma unroll
            for (int k = 0; k < 16; ++k) a2[r][k] = sB2[k];
#pragma unroll 8
        for (int j = 0; j < 32; ++j) {
#pragma unroll
            for (int kq = 0; kq < 4; ++kq) {
                float4 w = ((const float4*)sW2)[j * 4 + kq];
#pragma unroll
                for (int r = 0; r < 2; ++r) {
                    a2[r][kq * 4 + 0] = fmaf(a1[r][j], w.x, a2[r][kq * 4 + 0]);
                    a2[r][kq * 4 + 1] = fmaf(a1[r][j], w.y, a2[r][kq * 4 + 1]);
                    a2[r][kq * 4 + 2] = fmaf(a1[r][j], w.z, a2[r][kq * 4 + 2]);
                    a2[r][kq * 4 + 3] = fmaf(a1[r][j], w.w, a2[r][kq * 4 + 3]);
                }
            }
        }
#pragma unroll
        for (int r = 0; r < 2; ++r)
#pragma unroll
            for (int k = 0; k < 16; ++k) a2[r][k] = fmaxf(a2[r][k], 0.f);

        float a3[2][8];
#pragma unroll
        for (int r = 0; r < 2; ++r)
#pragma unroll
            for (int k = 0; k < 8; ++k) a3[r][k] = sB3[k];
#pragma unroll
        for (int j = 0; j < 16; ++j) {
#pragma unroll
            for (int kq = 0; kq < 2; ++kq) {
                float4 w = ((const float4*)sW3)[j * 2 + kq];
#pragma unroll
                for (int r = 0; r < 2; ++r) {
                    a3[r][kq * 4 + 0] = fmaf(a2[r][j], w.x, a3[r][kq * 4 + 0]);
                    a3[r][kq * 4 + 1] = fmaf(a2[r][j], w.y, a3[r][kq * 4 + 1]);
                    a3[r][kq * 4 + 2] = fmaf(a2[r][j], w.z, a3[r][kq * 4 + 2]);
                    a3[r][kq * 4 + 3] = fmaf(a2[r][j], w.w, a3[r][kq * 4 + 3]);
                }
            }
        }

#pragma unroll
        for (int r = 0; r < 2; ++r) {
            float p0 = sB4[0], p1 = sB4[1];
#pragma unroll
            for (int j = 0; j < 8; ++j) {
                float aj = fmaxf(a3[r][j], 0.f);
                p0 = fmaf(aj, sW4[j * 2 + 0], p0);
                p1 = fmaf(aj, sW4[j * 2 + 1], p1);
            }
            int row = (r == 0) ? r0 : r1;
            bool vr = (r == 0) ? v0 : v1;
            if (vr) {
                ((float2*)phi)[row] = make_float2(p0, p1);
                // stable softplus == jax.nn.softplus
                float sp = fmaxf(p1, 0.f) + log1pf(expf(-fabsf(p1)));
                float z = (y[r] - p0) / sp;
                lp_acc += fmaf(-0.5f * z, z, -logf(sp)) - HALF_LOG_2PI;
            }
        }
    }

    // ---- log-prob: block reduce -> global atomic; last ticket finalizes ----
#pragma unroll
    for (int m = 32; m >= 1; m >>= 1) lp_acc += __shfl_xor(lp_acc, m, 64);
    if (lane == 0) lred[wv] = lp_acc;
    __syncthreads();
    if (tid == 0) {
        float s = 0.f;
#pragma unroll
        for (int w = 0; w < TPB / 64; ++w) s += lred[w];
        atomicAdd(lpsum, s);
        __threadfence();
        unsigned t = atomicAdd(cnt2, 1u);
        if (t == gridDim.x - 1)
            outlp[0] = atomicAdd(lpsum, 0.0f) / (float)n_tgt;
    }
}

extern "C" void kernel_launch(void* const* d_in, const int* in_sizes, int n_in,
                              void* d_out, int out_size, void* d_ws, size_t ws_size,
                              hipStream_t stream)
{
    const float* O    = (const float*)d_in[0];
    const float* T    = (const float*)d_in[1];
    const float* h_W0 = (const float*)d_in[2];
    const float* h_b0 = (const float*)d_in[3];
    const float* h_W1 = (const float*)d_in[4];
    const float* h_b1 = (const float*)d_in[5];
    const float* h_W2 = (const float*)d_in[6];
    const float* h_b2 = (const float*)d_in[7];
    const float* g_W0 = (const float*)d_in[8];
    const float* g_b0 = (const float*)d_in[9];
    const float* g_W1 = (const float*)d_in[10];
    const float* g_b1 = (const float*)d_in[11];
    const float* g_W2 = (const float*)d_in[12];
    const float* g_b2 = (const float*)d_in[13];
    const float* g_W3 = (const float*)d_in[14];
    const float* g_b3 = (const float*)d_in[15];
    const float* g_W4 = (const float*)d_in[16];
    const float* g_b4 = (const float*)d_in[17];

    int n_ctx = in_sizes[0] / 2;
    int n_tgt = in_sizes[1] / 2;

    float* ws = (float*)d_ws;
    unsigned* cnt1 = (unsigned*)ws;          // [0]
    unsigned* cnt2 = (unsigned*)(ws + 1);    // [1]
    float* lpsum   = ws + 2;                 // [2]
    float* gsum    = ws + 8;                 // [8..39]

    float* phi = (float*)d_out;                       // 2 * n_tgt
    float* lp  = (float*)d_out + (out_size - 1);      // scalar log_prob

    hipMemsetAsync(d_ws, 0, 40 * sizeof(float), stream);
    fused_kernel<<<NBLK, TPB, 0, stream>>>(O, n_ctx, T, n_tgt,
                                           h_W0, h_b0, h_W1, h_b1, h_W2, h_b2,
                                           g_W0, g_b0, g_W1, g_b1, g_W2, g_b2,
                                           g_W3, g_b3, g_W4, g_b4,
                                           cnt1, cnt2, lpsum, gsum, phi, lp);
}

// Round 19
// 137.811 us; speedup vs baseline: 1.9422x; 1.9422x over previous
//
#include <hip/hip_runtime.h>
#include <math.h>

#define TPB 256
#define ENC_G 256
#define DEC_G 256
#define HALF_LOG_2PI 0.91893853320467274178f

// ws float layout: [0]=ticket(u32) [1]=lpsum [8..39]=gsum[32]; memset to 0.

// ---------------------------------------------------------------------------
// Kernel 1: encoder. Grid-stride over O rows; MLP 2->8(relu)->32(relu);
// block-reduce the 32 relu'd column sums; ONE-SHOT atomicAdd per block into
// gsum (256 blocks x 32 atomics = 8K total — benign; r14's spin barrier with
// its 1.7M-atomic storm is gone). Last encoder layer folded into kernel 2.
// ---------------------------------------------------------------------------
__global__ __launch_bounds__(TPB) void enc_kernel(
    const float* __restrict__ O, int n_ctx,
    const float* __restrict__ W0, const float* __restrict__ b0,
    const float* __restrict__ W1, const float* __restrict__ b1,
    float* __restrict__ gsum)
{
    __shared__ __align__(16) float sW0[16], sB0[8], sW1[256], sB1[32];
    __shared__ float xred[TPB / 64][32];
    int tid = threadIdx.x;
    if (tid < 16) sW0[tid] = W0[tid];
    if (tid < 8)  sB0[tid] = b0[tid];
    if (tid < 64) ((float4*)sW1)[tid] = ((const float4*)W1)[tid];
    if (tid < 32) sB1[tid] = b1[tid];
    __syncthreads();

    int nthreads = gridDim.x * TPB;
    float acc[32];
#pragma unroll
    for (int k = 0; k < 32; ++k) acc[k] = 0.f;

    for (int row = blockIdx.x * TPB + tid; row < n_ctx; row += nthreads) {
        float2 o = ((const float2*)O)[row];
        float a1[32];
#pragma unroll
        for (int k = 0; k < 32; ++k) a1[k] = sB1[k];
#pragma unroll
        for (int j = 0; j < 8; ++j) {
            float a0 = fmaxf(fmaf(o.x, sW0[j], fmaf(o.y, sW0[8 + j], sB0[j])), 0.f);
#pragma unroll
            for (int kq = 0; kq < 8; ++kq) {
                float4 w = ((const float4*)sW1)[j * 8 + kq];
                a1[kq * 4 + 0] = fmaf(a0, w.x, a1[kq * 4 + 0]);
                a1[kq * 4 + 1] = fmaf(a0, w.y, a1[kq * 4 + 1]);
                a1[kq * 4 + 2] = fmaf(a0, w.z, a1[kq * 4 + 2]);
                a1[kq * 4 + 3] = fmaf(a0, w.w, a1[kq * 4 + 3]);
            }
        }
#pragma unroll
        for (int k = 0; k < 32; ++k) acc[k] += fmaxf(a1[k], 0.f);
    }

    int lane = tid & 63, wv = tid >> 6;
#pragma unroll
    for (int k = 0; k < 32; ++k) {
        float v = acc[k];
#pragma unroll
        for (int m = 32; m >= 1; m >>= 1) v += __shfl_xor(v, m, 64);
        acc[k] = v;
    }
    if (lane == 0) {
#pragma unroll
        for (int k = 0; k < 32; ++k) xred[wv][k] = acc[k];
    }
    __syncthreads();
    if (tid < 32) {
        float s = 0.f;
#pragma unroll
        for (int w = 0; w < TPB / 64; ++w) s += xred[w][tid];
        atomicAdd(&gsum[tid], s);
    }
}

// ---------------------------------------------------------------------------
// Kernel 2: mid (redundant per block, ~200cyc) + decoder + logp finalize.
// Per block: a2mean from gsum -> r -> rW0 (sL0), stage weights in LDS,
// grid-stride decode 2 rows/thread/iter (r13's known-good body), one
// atomicAdd(lpsum) per block, last-ticket block writes the mean. 256 blocks
// = 1/CU exactly (r13's 391 blocks had a 2:1 CU load imbalance).
// ---------------------------------------------------------------------------
__global__ __launch_bounds__(TPB, 2) void dec_kernel(
    const float* __restrict__ T, int n_tgt, int n_ctx,
    const float* __restrict__ gsum,
    const float* __restrict__ hW2, const float* __restrict__ hb2,
    const float* __restrict__ gW0, const float* __restrict__ gb0,
    const float* __restrict__ W1, const float* __restrict__ b1,
    const float* __restrict__ W2, const float* __restrict__ b2,
    const float* __restrict__ W3, const float* __restrict__ b3,
    const float* __restrict__ W4, const float* __restrict__ b4,
    unsigned* __restrict__ ticket, float* __restrict__ lpsum,
    float* __restrict__ phi, float* __restrict__ outlp)
{
    __shared__ __align__(16) float sW1[2048], sB1[32], sW2[512], sB2[16];
    __shared__ __align__(16) float sW3[128], sB3[8], sW4[16], sB4[2];
    __shared__ __align__(16) float2 sL0[64];
    __shared__ float a2m[32], rl[128];
    __shared__ float lred[TPB / 64];
    int tid = threadIdx.x;

    ((float4*)sW1)[tid]       = ((const float4*)W1)[tid];
    ((float4*)sW1)[256 + tid] = ((const float4*)W1)[256 + tid];
    if (tid < 128) ((float4*)sW2)[tid] = ((const float4*)W2)[tid];
    if (tid < 32)  ((float4*)sW3)[tid] = ((const float4*)W3)[tid];
    if (tid < 32)  sB1[tid] = b1[tid];
    if (tid < 16)  sB2[tid] = b2[tid];
    if (tid < 8)   sB3[tid] = b3[tid];
    if (tid < 16)  sW4[tid] = W4[tid];
    if (tid < 2)   sB4[tid] = b4[tid];
    if (tid < 32)  a2m[tid] = gsum[tid] / (float)n_ctx;
    __syncthreads();

    // redundant mid: r = a2m @ hW2 + hb2; sL0 = (r @ gW0[:128] + gb0, gW0[128])
    if (tid < 128) {
        float v = hb2[tid];
#pragma unroll
        for (int j = 0; j < 32; ++j) v = fmaf(a2m[j], hW2[j * 128 + tid], v);
        rl[tid] = v;
    }
    __syncthreads();
    if (tid < 64) {
        float v = gb0[tid];
#pragma unroll
        for (int i = 0; i < 128; ++i) v = fmaf(rl[i], gW0[i * 64 + tid], v);
        sL0[tid] = make_float2(v, gW0[128 * 64 + tid]);
    }
    __syncthreads();

    float lp_acc = 0.f;
    int nchunk_rows = gridDim.x * TPB * 2;
    for (int cb = blockIdx.x * TPB * 2; cb < n_tgt; cb += nchunk_rows) {
        int r0 = cb + tid, r1 = cb + TPB + tid;
        bool v0 = r0 < n_tgt, v1 = r1 < n_tgt;
        float2 t0 = v0 ? ((const float2*)T)[r0] : make_float2(0.f, 0.f);
        float2 t1 = v1 ? ((const float2*)T)[r1] : make_float2(0.f, 0.f);
        float x[2] = { t0.x, t1.x }, y[2] = { t0.y, t1.y };

        float a1[2][32];
#pragma unroll
        for (int r = 0; r < 2; ++r)
#pragma unroll
            for (int k = 0; k < 32; ++k) a1[r][k] = sB1[k];
#pragma unroll 4
        for (int j = 0; j < 64; ++j) {
            float2 l0 = sL0[j];
            float a0[2];
#pragma unroll
            for (int r = 0; r < 2; ++r)
                a0[r] = fmaxf(fmaf(x[r], l0.y, l0.x), 0.f);
#pragma unroll
            for (int kq = 0; kq < 8; ++kq) {
                float4 w = ((const float4*)sW1)[j * 8 + kq];
#pragma unroll
                for (int r = 0; r < 2; ++r) {
                    a1[r][kq * 4 + 0] = fmaf(a0[r], w.x, a1[r][kq * 4 + 0]);
                    a1[r][kq * 4 + 1] = fmaf(a0[r], w.y, a1[r][kq * 4 + 1]);
                    a1[r][kq * 4 + 2] = fmaf(a0[r], w.z, a1[r][kq * 4 + 2]);
                    a1[r][kq * 4 + 3] = fmaf(a0[r], w.w, a1[r][kq * 4 + 3]);
                }
            }
        }
#pragma unroll
        for (int r = 0; r < 2; ++r)
#pragma unroll
            for (int k = 0; k < 32; ++k) a1[r][k] = fmaxf(a1[r][k], 0.f);

        float a2[2][16];
#pragma unroll
        for (int r = 0; r < 2; ++r)
#pragma unroll
            for (int k = 0; k < 16; ++k) a2[r][k] = sB2[k];
#pragma unroll 8
        for (int j = 0; j < 32; ++j) {
#pragma unroll
            for (int kq = 0; kq < 4; ++kq) {
                float4 w = ((const float4*)sW2)[j * 4 + kq];
#pragma unroll
                for (int r = 0; r < 2; ++r) {
                    a2[r][kq * 4 + 0] = fmaf(a1[r][j], w.x, a2[r][kq * 4 + 0]);
                    a2[r][kq * 4 + 1] = fmaf(a1[r][j], w.y, a2[r][kq * 4 + 1]);
                    a2[r][kq * 4 + 2] = fmaf(a1[r][j], w.z, a2[r][kq * 4 + 2]);
                    a2[r][kq * 4 + 3] = fmaf(a1[r][j], w.w, a2[r][kq * 4 + 3]);
                }
            }
        }
#pragma unroll
        for (int r = 0; r < 2; ++r)
#pragma unroll
            for (int k = 0; k < 16; ++k) a2[r][k] = fmaxf(a2[r][k], 0.f);

        float a3[2][8];
#pragma unroll
        for (int r = 0; r < 2; ++r)
#pragma unroll
            for (int k = 0; k < 8; ++k) a3[r][k] = sB3[k];
#pragma unroll
        for (int j = 0; j < 16; ++j) {
#pragma unroll
            for (int kq = 0; kq < 2; ++kq) {
                float4 w = ((const float4*)sW3)[j * 2 + kq];
#pragma unroll
                for (int r = 0; r < 2; ++r) {
                    a3[r][kq * 4 + 0] = fmaf(a2[r][j], w.x, a3[r][kq * 4 + 0]);
                    a3[r][kq * 4 + 1] = fmaf(a2[r][j], w.y, a3[r][kq * 4 + 1]);
                    a3[r][kq * 4 + 2] = fmaf(a2[r][j], w.z, a3[r][kq * 4 + 2]);
                    a3[r][kq * 4 + 3] = fmaf(a2[r][j], w.w, a3[r][kq * 4 + 3]);
                }
            }
        }

#pragma unroll
        for (int r = 0; r < 2; ++r) {
            float p0 = sB4[0], p1 = sB4[1];
#pragma unroll
            for (int j = 0; j < 8; ++j) {
                float aj = fmaxf(a3[r][j], 0.f);
                p0 = fmaf(aj, sW4[j * 2 + 0], p0);
                p1 = fmaf(aj, sW4[j * 2 + 1], p1);
            }
            int row = (r == 0) ? r0 : r1;
            bool vr = (r == 0) ? v0 : v1;
            if (vr) {
                ((float2*)phi)[row] = make_float2(p0, p1);
                // stable softplus == jax.nn.softplus
                float sp = fmaxf(p1, 0.f) + log1pf(expf(-fabsf(p1)));
                float z = (y[r] - p0) / sp;
                lp_acc += fmaf(-0.5f * z, z, -logf(sp)) - HALF_LOG_2PI;
            }
        }
    }

    // block reduce -> one atomic per block; last ticket writes the mean
    int lane = tid & 63, wv = tid >> 6;
#pragma unroll
    for (int m = 32; m >= 1; m >>= 1) lp_acc += __shfl_xor(lp_acc, m, 64);
    if (lane == 0) lred[wv] = lp_acc;
    __syncthreads();
    if (tid == 0) {
        float s = 0.f;
#pragma unroll
        for (int w = 0; w < TPB / 64; ++w) s += lred[w];
        atomicAdd(lpsum, s);
        __threadfence();
        unsigned t = atomicAdd(ticket, 1u);
        if (t == gridDim.x - 1)
            outlp[0] = atomicAdd(lpsum, 0.0f) / (float)n_tgt;
    }
}

extern "C" void kernel_launch(void* const* d_in, const int* in_sizes, int n_in,
                              void* d_out, int out_size, void* d_ws, size_t ws_size,
                              hipStream_t stream)
{
    const float* O    = (const float*)d_in[0];
    const float* T    = (const float*)d_in[1];
    const float* h_W0 = (const float*)d_in[2];
    const float* h_b0 = (const float*)d_in[3];
    const float* h_W1 = (const float*)d_in[4];
    const float* h_b1 = (const float*)d_in[5];
    const float* h_W2 = (const float*)d_in[6];
    const float* h_b2 = (const float*)d_in[7];
    const float* g_W0 = (const float*)d_in[8];
    const float* g_b0 = (const float*)d_in[9];
    const float* g_W1 = (const float*)d_in[10];
    const float* g_b1 = (const float*)d_in[11];
    const float* g_W2 = (const float*)d_in[12];
    const float* g_b2 = (const float*)d_in[13];
    const float* g_W3 = (const float*)d_in[14];
    const float* g_b3 = (const float*)d_in[15];
    const float* g_W4 = (const float*)d_in[16];
    const float* g_b4 = (const float*)d_in[17];

    int n_ctx = in_sizes[0] / 2;
    int n_tgt = in_sizes[1] / 2;

    float* ws      = (float*)d_ws;
    unsigned* tick = (unsigned*)ws;     // [0]
    float* lpsum   = ws + 1;            // [1]
    float* gsum    = ws + 8;            // [8..39]

    float* phi = (float*)d_out;                    // 2 * n_tgt
    float* lp  = (float*)d_out + (out_size - 1);   // scalar log_prob

    hipMemsetAsync(d_ws, 0, 40 * sizeof(float), stream);
    enc_kernel<<<ENC_G, TPB, 0, stream>>>(O, n_ctx, h_W0, h_b0, h_W1, h_b1, gsum);
    dec_kernel<<<DEC_G, TPB, 0, stream>>>(T, n_tgt, n_ctx, gsum,
                                          h_W2, h_b2, g_W0, g_b0,
                                          g_W1, g_b1, g_W2, g_b2,
                                          g_W3, g_b3, g_W4, g_b4,
                                          tick, lpsum, phi, lp);
}